// Round 3
// baseline (119.276 us; speedup 1.0000x reference)
//
#include <hip/hip_runtime.h>

// LatticeGaussian: out = W @ U - U, W[i,j] = exp(-0.5*||ref_i - ref_j||^2)
// N=8192, C=16, D=5, fp32. Exact pairwise evaluation (VALU-bound, O(N^2)).
//
// Round 3 changes vs round 2 (lg_main 59us, VALUBusy 46%, Occ 31%):
//  - NSEG 32 -> 64: grid 2048 blocks = 8 blocks/CU = 32 waves/CU (max
//    occupancy) to hide s_load/exp latency.  [predict VALUBusy -> ~80%]
//  - Pre-kernel packs j-side into RefPack {log2e-scaled ref[5], scaled
//    -0.5|r|^2} (32B, s_load_dwordx8-friendly); inner exponent is
//    1 add + 5 FMA, w = exp2(e) (v_exp_f32, no per-j mul by log2e).
//  - U row loads stay block-uniform -> scalarized (s_load_dwordx16).
// Adaptive: NSEG=64 if ws fits, else 32, else atomic fallback.

#define N_ROWS 8192
#define C_CH   16
#define D_DIM  5
#define TPB    256
#define NIB    (N_ROWS / TPB)   // 32 i-chunks

#if __has_builtin(__builtin_amdgcn_exp2f)
#define EXP2(x) __builtin_amdgcn_exp2f(x)
#else
#define EXP2(x) exp2f(x)
#endif

#define LOG2E 1.4426950408889634f

struct alignas(32) RefPack {
    float s[8];   // s[0..4] = log2e * ref[j][d], s[5] = -0.5*log2e*|ref_j|^2
};

__global__ __launch_bounds__(TPB) void lg_pre(const float* __restrict__ ref,
                                              RefPack* __restrict__ pack) {
    const int j = blockIdx.x * TPB + threadIdx.x;
    float v0 = ref[j * D_DIM + 0];
    float v1 = ref[j * D_DIM + 1];
    float v2 = ref[j * D_DIM + 2];
    float v3 = ref[j * D_DIM + 3];
    float v4 = ref[j * D_DIM + 4];
    float s = v0 * v0;
    s = fmaf(v1, v1, s); s = fmaf(v2, v2, s);
    s = fmaf(v3, v3, s); s = fmaf(v4, v4, s);
    RefPack p;
    p.s[0] = v0 * LOG2E; p.s[1] = v1 * LOG2E; p.s[2] = v2 * LOG2E;
    p.s[3] = v3 * LOG2E; p.s[4] = v4 * LOG2E;
    p.s[5] = -0.5f * LOG2E * s;
    p.s[6] = 0.0f; p.s[7] = 0.0f;
    pack[j] = p;
}

template <int NSEG>
__global__ __launch_bounds__(TPB) void lg_main(const float* __restrict__ U,
                                               const float* __restrict__ ref,
                                               const RefPack* __restrict__ pack,
                                               float* __restrict__ part) {
    constexpr int JPB = N_ROWS / NSEG;
    const int bid = blockIdx.x;
    const int ib  = bid % NIB;
    const int seg = bid / NIB;
    const int i   = ib * TPB + threadIdx.x;

    const float r0 = ref[i * D_DIM + 0];
    const float r1 = ref[i * D_DIM + 1];
    const float r2 = ref[i * D_DIM + 2];
    const float r3 = ref[i * D_DIM + 3];
    const float r4 = ref[i * D_DIM + 4];
    float ai = r0 * r0;
    ai = fmaf(r1, r1, ai); ai = fmaf(r2, r2, ai);
    ai = fmaf(r3, r3, ai); ai = fmaf(r4, r4, ai);
    ai = -0.5f * LOG2E * ai;   // log2e * (-0.5*|ri|^2)

    float acc[C_CH];
#pragma unroll
    for (int c = 0; c < C_CH; ++c) acc[c] = 0.0f;

    const float4* __restrict__ U4 = reinterpret_cast<const float4*>(U);

    const int j0 = seg * JPB;
#pragma unroll 4
    for (int j = j0; j < j0 + JPB; ++j) {
        // j is block-uniform: these scalarize (s_load_dwordx8 / dwordx16).
        const RefPack rp = pack[j];

        float e = ai + rp.s[5];
        e = fmaf(r0, rp.s[0], e);
        e = fmaf(r1, rp.s[1], e);
        e = fmaf(r2, rp.s[2], e);
        e = fmaf(r3, rp.s[3], e);
        e = fmaf(r4, rp.s[4], e);      // e = log2e * (-0.5*d^2)
        const float w = EXP2(e);

        const float4 u0 = U4[j * 4 + 0];
        const float4 u1 = U4[j * 4 + 1];
        const float4 u2 = U4[j * 4 + 2];
        const float4 u3 = U4[j * 4 + 3];

        acc[0]  = fmaf(w, u0.x, acc[0]);   acc[1]  = fmaf(w, u0.y, acc[1]);
        acc[2]  = fmaf(w, u0.z, acc[2]);   acc[3]  = fmaf(w, u0.w, acc[3]);
        acc[4]  = fmaf(w, u1.x, acc[4]);   acc[5]  = fmaf(w, u1.y, acc[5]);
        acc[6]  = fmaf(w, u1.z, acc[6]);   acc[7]  = fmaf(w, u1.w, acc[7]);
        acc[8]  = fmaf(w, u2.x, acc[8]);   acc[9]  = fmaf(w, u2.y, acc[9]);
        acc[10] = fmaf(w, u2.z, acc[10]);  acc[11] = fmaf(w, u2.w, acc[11]);
        acc[12] = fmaf(w, u3.x, acc[12]);  acc[13] = fmaf(w, u3.y, acc[13]);
        acc[14] = fmaf(w, u3.z, acc[14]);  acc[15] = fmaf(w, u3.w, acc[15]);
    }

    float4* p4 = reinterpret_cast<float4*>(part + ((size_t)seg * N_ROWS + i) * C_CH);
    p4[0] = make_float4(acc[0], acc[1], acc[2], acc[3]);
    p4[1] = make_float4(acc[4], acc[5], acc[6], acc[7]);
    p4[2] = make_float4(acc[8], acc[9], acc[10], acc[11]);
    p4[3] = make_float4(acc[12], acc[13], acc[14], acc[15]);
}

template <int NSEG>
__global__ __launch_bounds__(TPB) void lg_reduce(const float* __restrict__ U,
                                                 const float* __restrict__ part,
                                                 float* __restrict__ out) {
    const int t = blockIdx.x * TPB + threadIdx.x;  // float4 index, 32768 total
    const float4 u = reinterpret_cast<const float4*>(U)[t];
    float4 s = make_float4(-u.x, -u.y, -u.z, -u.w);
    const float4* p = reinterpret_cast<const float4*>(part);
#pragma unroll 8
    for (int seg = 0; seg < NSEG; ++seg) {
        const float4 v = p[(size_t)seg * (N_ROWS * C_CH / 4) + t];
        s.x += v.x; s.y += v.y; s.z += v.z; s.w += v.w;
    }
    reinterpret_cast<float4*>(out)[t] = s;
}

// ---- Fallback path (ws too small): direct distance + atomics ----

__global__ __launch_bounds__(TPB) void lg_init(const float* __restrict__ U,
                                               float* __restrict__ out) {
    const int idx = blockIdx.x * TPB + threadIdx.x;
    if (idx < N_ROWS * C_CH) out[idx] = -U[idx];
}

__global__ __launch_bounds__(TPB) void lg_main_atomic(const float* __restrict__ U,
                                                      const float* __restrict__ ref,
                                                      float* __restrict__ out) {
    constexpr int NSEG = 32;
    constexpr int JPB  = N_ROWS / NSEG;
    const int bid = blockIdx.x;
    const int ib  = bid % NIB;
    const int seg = bid / NIB;
    const int i   = ib * TPB + threadIdx.x;

    const float r0 = ref[i * D_DIM + 0];
    const float r1 = ref[i * D_DIM + 1];
    const float r2 = ref[i * D_DIM + 2];
    const float r3 = ref[i * D_DIM + 3];
    const float r4 = ref[i * D_DIM + 4];

    float acc[C_CH];
#pragma unroll
    for (int c = 0; c < C_CH; ++c) acc[c] = 0.0f;

    const float4* __restrict__ U4 = reinterpret_cast<const float4*>(U);
    const int j0 = seg * JPB;
#pragma unroll 4
    for (int j = j0; j < j0 + JPB; ++j) {
        const float d0 = r0 - ref[j * D_DIM + 0];
        const float d1 = r1 - ref[j * D_DIM + 1];
        const float d2 = r2 - ref[j * D_DIM + 2];
        const float d3 = r3 - ref[j * D_DIM + 3];
        const float d4 = r4 - ref[j * D_DIM + 4];
        float dsq = d0 * d0;
        dsq = fmaf(d1, d1, dsq); dsq = fmaf(d2, d2, dsq);
        dsq = fmaf(d3, d3, dsq); dsq = fmaf(d4, d4, dsq);
        const float w = __expf(-0.5f * dsq);

        const float4 u0 = U4[j * 4 + 0];
        const float4 u1 = U4[j * 4 + 1];
        const float4 u2 = U4[j * 4 + 2];
        const float4 u3 = U4[j * 4 + 3];
        acc[0]  = fmaf(w, u0.x, acc[0]);   acc[1]  = fmaf(w, u0.y, acc[1]);
        acc[2]  = fmaf(w, u0.z, acc[2]);   acc[3]  = fmaf(w, u0.w, acc[3]);
        acc[4]  = fmaf(w, u1.x, acc[4]);   acc[5]  = fmaf(w, u1.y, acc[5]);
        acc[6]  = fmaf(w, u1.z, acc[6]);   acc[7]  = fmaf(w, u1.w, acc[7]);
        acc[8]  = fmaf(w, u2.x, acc[8]);   acc[9]  = fmaf(w, u2.y, acc[9]);
        acc[10] = fmaf(w, u2.z, acc[10]);  acc[11] = fmaf(w, u2.w, acc[11]);
        acc[12] = fmaf(w, u3.x, acc[12]);  acc[13] = fmaf(w, u3.y, acc[13]);
        acc[14] = fmaf(w, u3.z, acc[14]);  acc[15] = fmaf(w, u3.w, acc[15]);
    }

    float* o = out + (size_t)i * C_CH;
#pragma unroll
    for (int c = 0; c < C_CH; ++c) atomicAdd(&o[c], acc[c]);
}

extern "C" void kernel_launch(void* const* d_in, const int* in_sizes, int n_in,
                              void* d_out, int out_size, void* d_ws, size_t ws_size,
                              hipStream_t stream) {
    const float* U   = (const float*)d_in[0];   // [8192,16]
    const float* ref = (const float*)d_in[1];   // [8192,5]
    float* out       = (float*)d_out;           // [8192,16]

    const size_t pack_bytes = (size_t)N_ROWS * sizeof(RefPack);
    const size_t part_elems = [](int nseg) {
        return (size_t)nseg * N_ROWS * C_CH;
    }(1);  // per-seg elems helper (N_ROWS*C_CH)

    const size_t need64 = pack_bytes + 64 * part_elems * sizeof(float);
    const size_t need32 = pack_bytes + 32 * part_elems * sizeof(float);

    if (ws_size >= need64) {
        RefPack* pack = (RefPack*)d_ws;
        float* part   = (float*)((char*)d_ws + pack_bytes);
        hipLaunchKernelGGL(lg_pre, dim3(N_ROWS / TPB), dim3(TPB), 0, stream, ref, pack);
        hipLaunchKernelGGL((lg_main<64>), dim3(NIB * 64), dim3(TPB), 0, stream,
                           U, ref, pack, part);
        hipLaunchKernelGGL((lg_reduce<64>), dim3(N_ROWS * C_CH / 4 / TPB), dim3(TPB),
                           0, stream, U, part, out);
    } else if (ws_size >= need32) {
        RefPack* pack = (RefPack*)d_ws;
        float* part   = (float*)((char*)d_ws + pack_bytes);
        hipLaunchKernelGGL(lg_pre, dim3(N_ROWS / TPB), dim3(TPB), 0, stream, ref, pack);
        hipLaunchKernelGGL((lg_main<32>), dim3(NIB * 32), dim3(TPB), 0, stream,
                           U, ref, pack, part);
        hipLaunchKernelGGL((lg_reduce<32>), dim3(N_ROWS * C_CH / 4 / TPB), dim3(TPB),
                           0, stream, U, part, out);
    } else {
        hipLaunchKernelGGL(lg_init, dim3((N_ROWS * C_CH + TPB - 1) / TPB), dim3(TPB),
                           0, stream, U, out);
        hipLaunchKernelGGL(lg_main_atomic, dim3(NIB * 32), dim3(TPB), 0, stream,
                           U, ref, out);
    }
}

// Round 6
// 104.737 us; speedup vs baseline: 1.1388x; 1.1388x over previous
//
#include <hip/hip_runtime.h>

// LatticeGaussian: out = W @ U - U, W[i,j] = exp(-0.5*||ref_i - ref_j||^2)
// N=8192, C=16, D=5, fp32. Exact pairwise evaluation (VALU-bound, O(N^2)).
//
// R6 == R5 (two consecutive GPU timeouts; experiment still pending).
// Rationale vs R3 (lg_main 63us, VALUBusy 42%): stall was per-j uniform
// global loads (scalar-L1 thrash, ~200cy L2 latency, <=2 iters in flight).
//  - LDS-stage each block's j-segment (ref -> log2e-scaled pack computed
//    in-place; U rows copied): inner loop reads are uniform ds_read_b128
//    (broadcast, conflict-free, short latency).
//  - MI=2 i-rows per thread: 2x VALU work per j-load.
//  - Grid: NIB=16 i-chunks x NSEG=64 segments = 1024 blocks x 256 thr.
//    Partials 33.5MB -> lg_reduce folds -U. Fallbacks: NSEG=32, atomics.

#define N_ROWS 8192
#define C_CH   16
#define D_DIM  5
#define TPB    256
#define MI     2
#define IPB    (TPB * MI)        // 512 i per block
#define NIB    (N_ROWS / IPB)    // 16 i-chunks

#if __has_builtin(__builtin_amdgcn_exp2f)
#define EXP2(x) __builtin_amdgcn_exp2f(x)
#else
#define EXP2(x) exp2f(x)
#endif

#define LOG2E 1.4426950408889634f

template <int NSEG>
__global__ __launch_bounds__(TPB) void lg_main(const float* __restrict__ U,
                                               const float* __restrict__ ref,
                                               float* __restrict__ part) {
    constexpr int JPB = N_ROWS / NSEG;   // 128 (NSEG=64) or 256 (NSEG=32)

    __shared__ float sj[JPB][8];    // [0..4]=log2e*ref, [5]=-0.5*log2e*|r|^2
    __shared__ float su[JPB][16];   // U rows

    const int bid = blockIdx.x;
    const int ib  = bid % NIB;
    const int seg = bid / NIB;
    const int tid = threadIdx.x;
    const int j0  = seg * JPB;

    // ---- Per-thread i-rows: issue global loads early (overlap staging) ----
    const int i0 = ib * IPB + tid;
    const int i1 = i0 + TPB;
    const float r00 = ref[i0 * D_DIM + 0], r10 = ref[i1 * D_DIM + 0];
    const float r01 = ref[i0 * D_DIM + 1], r11 = ref[i1 * D_DIM + 1];
    const float r02 = ref[i0 * D_DIM + 2], r12 = ref[i1 * D_DIM + 2];
    const float r03 = ref[i0 * D_DIM + 3], r13 = ref[i1 * D_DIM + 3];
    const float r04 = ref[i0 * D_DIM + 4], r14 = ref[i1 * D_DIM + 4];

    // ---- Stage j-segment into LDS (compute pack from ref in-place) ----
    for (int jj = tid; jj < JPB; jj += TPB) {
        const int j = j0 + jj;
        const float v0 = ref[j * D_DIM + 0];
        const float v1 = ref[j * D_DIM + 1];
        const float v2 = ref[j * D_DIM + 2];
        const float v3 = ref[j * D_DIM + 3];
        const float v4 = ref[j * D_DIM + 4];
        float s = v0 * v0;
        s = fmaf(v1, v1, s); s = fmaf(v2, v2, s);
        s = fmaf(v3, v3, s); s = fmaf(v4, v4, s);
        sj[jj][0] = v0 * LOG2E; sj[jj][1] = v1 * LOG2E;
        sj[jj][2] = v2 * LOG2E; sj[jj][3] = v3 * LOG2E;
        sj[jj][4] = v4 * LOG2E; sj[jj][5] = -0.5f * LOG2E * s;
        sj[jj][6] = 0.0f;       sj[jj][7] = 0.0f;
    }
    {
        const float4* __restrict__ U4 = reinterpret_cast<const float4*>(U);
        float4* su4 = reinterpret_cast<float4*>(&su[0][0]);
        for (int idx = tid; idx < JPB * 4; idx += TPB)
            su4[idx] = U4[(size_t)j0 * 4 + idx];
    }
    __syncthreads();

    float a0 = r00 * r00, a1 = r10 * r10;
    a0 = fmaf(r01, r01, a0); a1 = fmaf(r11, r11, a1);
    a0 = fmaf(r02, r02, a0); a1 = fmaf(r12, r12, a1);
    a0 = fmaf(r03, r03, a0); a1 = fmaf(r13, r13, a1);
    a0 = fmaf(r04, r04, a0); a1 = fmaf(r14, r14, a1);
    a0 *= -0.5f * LOG2E;     a1 *= -0.5f * LOG2E;

    float acc0[C_CH], acc1[C_CH];
#pragma unroll
    for (int c = 0; c < C_CH; ++c) { acc0[c] = 0.0f; acc1[c] = 0.0f; }

#pragma unroll 8
    for (int jj = 0; jj < JPB; ++jj) {
        const float4 sA = *reinterpret_cast<const float4*>(&sj[jj][0]);
        const float2 sB = *reinterpret_cast<const float2*>(&sj[jj][4]);

        float e0 = a0 + sB.y;
        float e1 = a1 + sB.y;
        e0 = fmaf(r00, sA.x, e0);  e1 = fmaf(r10, sA.x, e1);
        e0 = fmaf(r01, sA.y, e0);  e1 = fmaf(r11, sA.y, e1);
        e0 = fmaf(r02, sA.z, e0);  e1 = fmaf(r12, sA.z, e1);
        e0 = fmaf(r03, sA.w, e0);  e1 = fmaf(r13, sA.w, e1);
        e0 = fmaf(r04, sB.x, e0);  e1 = fmaf(r14, sB.x, e1);
        const float w0 = EXP2(e0);
        const float w1 = EXP2(e1);

        const float4 u0 = *reinterpret_cast<const float4*>(&su[jj][0]);
        const float4 u1 = *reinterpret_cast<const float4*>(&su[jj][4]);
        const float4 u2 = *reinterpret_cast<const float4*>(&su[jj][8]);
        const float4 u3 = *reinterpret_cast<const float4*>(&su[jj][12]);

        acc0[0]  = fmaf(w0, u0.x, acc0[0]);   acc1[0]  = fmaf(w1, u0.x, acc1[0]);
        acc0[1]  = fmaf(w0, u0.y, acc0[1]);   acc1[1]  = fmaf(w1, u0.y, acc1[1]);
        acc0[2]  = fmaf(w0, u0.z, acc0[2]);   acc1[2]  = fmaf(w1, u0.z, acc1[2]);
        acc0[3]  = fmaf(w0, u0.w, acc0[3]);   acc1[3]  = fmaf(w1, u0.w, acc1[3]);
        acc0[4]  = fmaf(w0, u1.x, acc0[4]);   acc1[4]  = fmaf(w1, u1.x, acc1[4]);
        acc0[5]  = fmaf(w0, u1.y, acc0[5]);   acc1[5]  = fmaf(w1, u1.y, acc1[5]);
        acc0[6]  = fmaf(w0, u1.z, acc0[6]);   acc1[6]  = fmaf(w1, u1.z, acc1[6]);
        acc0[7]  = fmaf(w0, u1.w, acc0[7]);   acc1[7]  = fmaf(w1, u1.w, acc1[7]);
        acc0[8]  = fmaf(w0, u2.x, acc0[8]);   acc1[8]  = fmaf(w1, u2.x, acc1[8]);
        acc0[9]  = fmaf(w0, u2.y, acc0[9]);   acc1[9]  = fmaf(w1, u2.y, acc1[9]);
        acc0[10] = fmaf(w0, u2.z, acc0[10]);  acc1[10] = fmaf(w1, u2.z, acc1[10]);
        acc0[11] = fmaf(w0, u2.w, acc0[11]);  acc1[11] = fmaf(w1, u2.w, acc1[11]);
        acc0[12] = fmaf(w0, u3.x, acc0[12]);  acc1[12] = fmaf(w1, u3.x, acc1[12]);
        acc0[13] = fmaf(w0, u3.y, acc0[13]);  acc1[13] = fmaf(w1, u3.y, acc1[13]);
        acc0[14] = fmaf(w0, u3.z, acc0[14]);  acc1[14] = fmaf(w1, u3.z, acc1[14]);
        acc0[15] = fmaf(w0, u3.w, acc0[15]);  acc1[15] = fmaf(w1, u3.w, acc1[15]);
    }

    float4* p0 = reinterpret_cast<float4*>(part + ((size_t)seg * N_ROWS + i0) * C_CH);
    float4* p1 = reinterpret_cast<float4*>(part + ((size_t)seg * N_ROWS + i1) * C_CH);
    p0[0] = make_float4(acc0[0],  acc0[1],  acc0[2],  acc0[3]);
    p0[1] = make_float4(acc0[4],  acc0[5],  acc0[6],  acc0[7]);
    p0[2] = make_float4(acc0[8],  acc0[9],  acc0[10], acc0[11]);
    p0[3] = make_float4(acc0[12], acc0[13], acc0[14], acc0[15]);
    p1[0] = make_float4(acc1[0],  acc1[1],  acc1[2],  acc1[3]);
    p1[1] = make_float4(acc1[4],  acc1[5],  acc1[6],  acc1[7]);
    p1[2] = make_float4(acc1[8],  acc1[9],  acc1[10], acc1[11]);
    p1[3] = make_float4(acc1[12], acc1[13], acc1[14], acc1[15]);
}

template <int NSEG>
__global__ __launch_bounds__(TPB) void lg_reduce(const float* __restrict__ U,
                                                 const float* __restrict__ part,
                                                 float* __restrict__ out) {
    const int t = blockIdx.x * TPB + threadIdx.x;  // float4 index, 32768 total
    const float4 u = reinterpret_cast<const float4*>(U)[t];
    float4 s = make_float4(-u.x, -u.y, -u.z, -u.w);
    const float4* p = reinterpret_cast<const float4*>(part);
#pragma unroll 8
    for (int seg = 0; seg < NSEG; ++seg) {
        const float4 v = p[(size_t)seg * (N_ROWS * C_CH / 4) + t];
        s.x += v.x; s.y += v.y; s.z += v.z; s.w += v.w;
    }
    reinterpret_cast<float4*>(out)[t] = s;
}

// ---- Last-resort fallback (ws too small): init -U + atomics ----

__global__ __launch_bounds__(TPB) void lg_init(const float* __restrict__ U,
                                               float* __restrict__ out) {
    const int idx = blockIdx.x * TPB + threadIdx.x;
    if (idx < N_ROWS * C_CH) out[idx] = -U[idx];
}

__global__ __launch_bounds__(TPB) void lg_main_atomic(const float* __restrict__ U,
                                                      const float* __restrict__ ref,
                                                      float* __restrict__ out) {
    constexpr int NSEG = 32;
    constexpr int JPB  = N_ROWS / NSEG;
    constexpr int NIB1 = N_ROWS / TPB;
    const int bid = blockIdx.x;
    const int ib  = bid % NIB1;
    const int seg = bid / NIB1;
    const int i   = ib * TPB + threadIdx.x;

    const float r0 = ref[i * D_DIM + 0];
    const float r1 = ref[i * D_DIM + 1];
    const float r2 = ref[i * D_DIM + 2];
    const float r3 = ref[i * D_DIM + 3];
    const float r4 = ref[i * D_DIM + 4];

    float acc[C_CH];
#pragma unroll
    for (int c = 0; c < C_CH; ++c) acc[c] = 0.0f;

    const float4* __restrict__ U4 = reinterpret_cast<const float4*>(U);
    const int j0 = seg * JPB;
#pragma unroll 4
    for (int j = j0; j < j0 + JPB; ++j) {
        const float d0 = r0 - ref[j * D_DIM + 0];
        const float d1 = r1 - ref[j * D_DIM + 1];
        const float d2 = r2 - ref[j * D_DIM + 2];
        const float d3 = r3 - ref[j * D_DIM + 3];
        const float d4 = r4 - ref[j * D_DIM + 4];
        float dsq = d0 * d0;
        dsq = fmaf(d1, d1, dsq); dsq = fmaf(d2, d2, dsq);
        dsq = fmaf(d3, d3, dsq); dsq = fmaf(d4, d4, dsq);
        const float w = __expf(-0.5f * dsq);

        const float4 u0 = U4[j * 4 + 0];
        const float4 u1 = U4[j * 4 + 1];
        const float4 u2 = U4[j * 4 + 2];
        const float4 u3 = U4[j * 4 + 3];
        acc[0]  = fmaf(w, u0.x, acc[0]);   acc[1]  = fmaf(w, u0.y, acc[1]);
        acc[2]  = fmaf(w, u0.z, acc[2]);   acc[3]  = fmaf(w, u0.w, acc[3]);
        acc[4]  = fmaf(w, u1.x, acc[4]);   acc[5]  = fmaf(w, u1.y, acc[5]);
        acc[6]  = fmaf(w, u1.z, acc[6]);   acc[7]  = fmaf(w, u1.w, acc[7]);
        acc[8]  = fmaf(w, u2.x, acc[8]);   acc[9]  = fmaf(w, u2.y, acc[9]);
        acc[10] = fmaf(w, u2.z, acc[10]);  acc[11] = fmaf(w, u2.w, acc[11]);
        acc[12] = fmaf(w, u3.x, acc[12]);  acc[13] = fmaf(w, u3.y, acc[13]);
        acc[14] = fmaf(w, u3.z, acc[14]);  acc[15] = fmaf(w, u3.w, acc[15]);
    }

    float* o = out + (size_t)i * C_CH;
#pragma unroll
    for (int c = 0; c < C_CH; ++c) atomicAdd(&o[c], acc[c]);
}

extern "C" void kernel_launch(void* const* d_in, const int* in_sizes, int n_in,
                              void* d_out, int out_size, void* d_ws, size_t ws_size,
                              hipStream_t stream) {
    const float* U   = (const float*)d_in[0];   // [8192,16]
    const float* ref = (const float*)d_in[1];   // [8192,5]
    float* out       = (float*)d_out;           // [8192,16]

    const size_t seg_bytes = (size_t)N_ROWS * C_CH * sizeof(float);
    const size_t need64 = 64 * seg_bytes;
    const size_t need32 = 32 * seg_bytes;

    if (ws_size >= need64) {
        float* part = (float*)d_ws;
        hipLaunchKernelGGL((lg_main<64>), dim3(NIB * 64), dim3(TPB), 0, stream,
                           U, ref, part);
        hipLaunchKernelGGL((lg_reduce<64>), dim3(N_ROWS * C_CH / 4 / TPB), dim3(TPB),
                           0, stream, U, part, out);
    } else if (ws_size >= need32) {
        float* part = (float*)d_ws;
        hipLaunchKernelGGL((lg_main<32>), dim3(NIB * 32), dim3(TPB), 0, stream,
                           U, ref, part);
        hipLaunchKernelGGL((lg_reduce<32>), dim3(N_ROWS * C_CH / 4 / TPB), dim3(TPB),
                           0, stream, U, part, out);
    } else {
        hipLaunchKernelGGL(lg_init, dim3((N_ROWS * C_CH + TPB - 1) / TPB), dim3(TPB),
                           0, stream, U, out);
        hipLaunchKernelGGL(lg_main_atomic, dim3((N_ROWS / TPB) * 32), dim3(TPB),
                           0, stream, U, ref, out);
    }
}